// Round 5
// baseline (168.447 us; speedup 1.0000x reference)
//
#include <hip/hip_runtime.h>

#define TWO_PI 6.2831853071795864769f

typedef float floatx4 __attribute__((ext_vector_type(4)));
typedef float f32x16 __attribute__((ext_vector_type(16)));
typedef __bf16 bf16x8 __attribute__((ext_vector_type(8)));

__device__ __forceinline__ unsigned short f32_to_bf16(float f) {
    unsigned int u = __float_as_uint(f);
    u += 0x7fffu + ((u >> 16) & 1u);   // round-to-nearest-even
    return (unsigned short)(u >> 16);
}

__device__ __forceinline__ void gload_lds16(const void* g, void* l) {
    __builtin_amdgcn_global_load_lds(
        (__attribute__((address_space(1))) unsigned int*)g,
        (__attribute__((address_space(3))) unsigned int*)l, 16, 0, 0);
}

// ---------------------------------------------------------------------------
// Fused coef-precompute + elementwise kernel.
// Block: 64 n-rows x 64 kq-cols, 256 threads.
// Phase A: compute per-kq coefs into LDS (cf[kql][32]):
//   Ac[0..7]=2pi*E_w, u[0..7]=(2pi*std_p)^2*vsw, z[0..7], alpha, sqrt(2w/K), 2w/K
// Phase B: main loop; per-block column partial sums written to part[by][kq]
//   (NO device atomics).
// ---------------------------------------------------------------------------
__global__ __launch_bounds__(256) void k_ephi(
    const float* __restrict__ X, const float* __restrict__ zc,
    const float* __restrict__ weight, const float* __restrict__ mu,
    const float* __restrict__ stdv, const float* __restrict__ alpha,
    const float* __restrict__ vmw, const float* __restrict__ vsw,
    float* __restrict__ Ephi, float* __restrict__ Ecos,
    unsigned short* __restrict__ ET, float* __restrict__ part, int N)
{
    __shared__ float cf[64][32];
    __shared__ float Xs[64][8];
    __shared__ unsigned short Ebf[64][66];   // [kq_local][n_local]
    __shared__ float red[256];

    const int tid = threadIdx.x;
    const int kq0 = blockIdx.x * 64;
    const int n0  = blockIdx.y * 64;

    // ---- Phase A: coefs (512 items over 256 threads) + X staging ----
    {
        int it = tid;
#pragma unroll
        for (int r = 0; r < 2; ++r, it += 256) {
            const int kql = it >> 3, d = it & 7;
            const int kq = kq0 + kql, q = kq & 15;
            float m = mu[d * 16 + q];
            float s = stdv[d * 16 + q];
            float mean_p = 1.0f / (m + 1e-8f);
            float std_p  = 1.0f / (TWO_PI * s + 1e-8f);
            float Ew  = mean_p + std_p * vmw[d * 1024 + kq];
            float sp2 = std_p * TWO_PI;
            cf[kql][d]      = TWO_PI * Ew;
            cf[kql][8 + d]  = sp2 * sp2 * vsw[d * 1024 + kq];
            cf[kql][16 + d] = zc[d * 1024 + kq];
        }
        if (tid < 64) {
            const int kq = kq0 + tid, q = kq & 15;
            float t2k = weight[q] * (2.0f / 64.0f);
            cf[tid][24] = alpha[kq];
            cf[tid][25] = sqrtf(t2k);
            cf[tid][26] = t2k;
        }
        for (int i = tid; i < 512; i += 256)
            Xs[i >> 3][i & 7] = X[(size_t)(n0 + (i >> 3)) * 8 + (i & 7)];
    }
    __syncthreads();

    const int kql = tid & 63;
    const int kq  = kq0 + kql;
    const int nb  = (tid >> 6) * 16;

    float Ac[8], u[8], zv[8];
    *(floatx4*)&Ac[0] = *(const floatx4*)&cf[kql][0];
    *(floatx4*)&Ac[4] = *(const floatx4*)&cf[kql][4];
    *(floatx4*)&u[0]  = *(const floatx4*)&cf[kql][8];
    *(floatx4*)&u[4]  = *(const floatx4*)&cf[kql][12];
    *(floatx4*)&zv[0] = *(const floatx4*)&cf[kql][16];
    *(floatx4*)&zv[4] = *(const floatx4*)&cf[kql][20];
    const float alp = cf[kql][24], sqw = cf[kql][25], t2k = cf[kql][26];

    float csum = 0.0f;
#pragma unroll 4
    for (int nl = 0; nl < 16; ++nl) {
        const int n = nb + nl;
        floatx4 xa = *(const floatx4*)&Xs[n][0];
        floatx4 xb = *(const floatx4*)&Xs[n][4];
        float ph = 0.0f, s = 0.0f;
#pragma unroll
        for (int d = 0; d < 4; ++d) {
            float t = xa[d] - zv[d];
            ph = fmaf(Ac[d], t, ph);
            s  = fmaf(u[d], t * t, s);
        }
#pragma unroll
        for (int d = 0; d < 4; ++d) {
            float t = xb[d] - zv[4 + d];
            ph = fmaf(Ac[4 + d], t, ph);
            s  = fmaf(u[4 + d], t * t, s);
        }
        float cw  = __cosf(alp + ph);           // |arg| <~ few hundred: err ~1e-5
        float dec = __expf(-0.5f * s);
        float ep  = sqw * dec * cw;
        float d2  = dec * dec;
        float c2w = fmaf(2.0f * cw, cw, -1.0f); // cos(2(alpha+phase))
        float ec  = t2k * fmaf(0.5f * d2 * d2, c2w, 0.5f);
        csum += ec;
        size_t idx = (size_t)(n0 + n) * 1024 + kq;
        Ephi[idx] = ep;
        Ecos[idx] = ec;
        Ebf[kql][n] = f32_to_bf16(ep);
    }
    red[tid] = csum;
    __syncthreads();
    if (tid < 64) {
        float v = red[tid] + red[tid + 64] + red[tid + 128] + red[tid + 192];
        part[(size_t)blockIdx.y * 1024 + kq0 + tid] = v;   // plain store, no atomics
    }

    // transposed bf16 tile: ET[kq0+row][n0 .. n0+63]; 8 lanes per 128B row
    const int rw = tid >> 3;
    const int cw8 = tid & 7;
#pragma unroll
    for (int cc = 0; cc < 2; ++cc) {
        const int row = rw + cc * 32;
        const unsigned short* s8 = &Ebf[row][cw8 * 8];
        uint4 v;
        v.x = (unsigned)s8[0] | ((unsigned)s8[1] << 16);
        v.y = (unsigned)s8[2] | ((unsigned)s8[3] << 16);
        v.z = (unsigned)s8[4] | ((unsigned)s8[5] << 16);
        v.w = (unsigned)s8[6] | ((unsigned)s8[7] << 16);
        *(uint4*)&ET[(size_t)(kq0 + row) * N + n0 + cw8 * 8] = v;
    }
}

// ---------------------------------------------------------------------------
// Gpart[z] = E^T E over n-chunk z. Flat 512-block grid, z = bid % 8 so all
// 64 tile-blocks of chunk z co-reside on XCD z and its 2MB ET slice stays
// L2-resident. 128x128 tile, 4 waves (2x2), BK=64, double-buffered LDS,
// XOR chunk swizzle, setprio around MFMA cluster.
// ---------------------------------------------------------------------------
__global__ __launch_bounds__(256) void k_gemm(
    const unsigned short* __restrict__ ET, float* __restrict__ Gpart,
    int N, int KQ)
{
    __shared__ unsigned short At[2][128 * 64];
    __shared__ unsigned short Bt[2][128 * 64];

    const int tid  = threadIdx.x;
    const int wave = tid >> 6, lane = tid & 63;
    const int wi = wave >> 1, wj = wave & 1;

    const int bid = blockIdx.x;
    const int zc  = bid & 7;            // split-K chunk == XCD (perf heuristic only)
    const int t8  = bid >> 3;           // 0..63 tile index
    const int i0  = (t8 >> 3) * 128;
    const int j0  = (t8 & 7) * 128;
    const int NS = N >> 3;              // 1024 per split
    const int nbase = zc * NS;
    const int nsteps = NS >> 6;         // 16

    const int srow = tid >> 3;
    const int sch  = (tid & 7) ^ (srow & 7);
    const size_t gA = (size_t)(i0 + srow) * N + nbase + sch * 8;
    const size_t gB = (size_t)(j0 + srow) * N + nbase + sch * 8;

    f32x16 acc[2][2] = {};

    auto STAGE = [&](int buf, int noff) {
        unsigned short* la = &At[buf][wave * 512];
        unsigned short* lb = &Bt[buf][wave * 512];
#pragma unroll
        for (int b = 0; b < 4; ++b) {
            gload_lds16(ET + gA + (size_t)(b * 32) * N + noff, la + b * 2048);
            gload_lds16(ET + gB + (size_t)(b * 32) * N + noff, lb + b * 2048);
        }
    };

    STAGE(0, 0);
    asm volatile("s_waitcnt vmcnt(0)" ::: "memory");
    __syncthreads();

    for (int t = 0; t < nsteps; ++t) {
        const int buf = t & 1;
        if (t + 1 < nsteps) STAGE(buf ^ 1, (t + 1) * 64);

        const unsigned short* Ab = &At[buf][0];
        const unsigned short* Bb = &Bt[buf][0];
        bf16x8 a[2][4], b[2][4];
#pragma unroll
        for (int m = 0; m < 2; ++m) {
            const int r = wi * 64 + m * 32 + (lane & 31);
#pragma unroll
            for (int ks = 0; ks < 4; ++ks) {
                const int ch = (ks * 2 + (lane >> 5)) ^ (r & 7);
                a[m][ks] = *(const bf16x8*)&Ab[r * 64 + ch * 8];
            }
        }
#pragma unroll
        for (int n = 0; n < 2; ++n) {
            const int r = wj * 64 + n * 32 + (lane & 31);
#pragma unroll
            for (int ks = 0; ks < 4; ++ks) {
                const int ch = (ks * 2 + (lane >> 5)) ^ (r & 7);
                b[n][ks] = *(const bf16x8*)&Bb[r * 64 + ch * 8];
            }
        }
        __builtin_amdgcn_s_setprio(1);
#pragma unroll
        for (int ks = 0; ks < 4; ++ks)
#pragma unroll
            for (int m = 0; m < 2; ++m)
#pragma unroll
                for (int n = 0; n < 2; ++n)
                    acc[m][n] = __builtin_amdgcn_mfma_f32_32x32x16_bf16(
                        a[m][ks], b[n][ks], acc[m][n], 0, 0, 0);
        __builtin_amdgcn_s_setprio(0);

        asm volatile("s_waitcnt vmcnt(0)" ::: "memory");
        __syncthreads();
    }

    // C/D layout (32x32): col = lane&31, row = (reg&3) + 8*(reg>>2) + 4*(lane>>5)
    float* Gp = Gpart + (size_t)zc * KQ * KQ;
    const int colb = j0 + wj * 64 + (lane & 31);
    const int rowb = i0 + wi * 64 + 4 * (lane >> 5);
#pragma unroll
    for (int m = 0; m < 2; ++m)
#pragma unroll
        for (int n = 0; n < 2; ++n)
#pragma unroll
            for (int reg = 0; reg < 16; ++reg) {
                const int row = rowb + m * 32 + (reg & 3) + 8 * (reg >> 2);
                Gp[(size_t)row * KQ + colb + n * 32] = acc[m][n][reg];
            }
}

// ---------------------------------------------------------------------------
// G = sum_z Gpart[z]; diag = colsum from per-block partials. float4/thread.
// ---------------------------------------------------------------------------
__global__ __launch_bounds__(256) void k_reduce(
    const float* __restrict__ Gpart, const float* __restrict__ part,
    float* __restrict__ G, int KQ, int NB)
{
    const size_t off = ((size_t)blockIdx.x * 256 + threadIdx.x) * 4;
    const size_t stride = (size_t)KQ * KQ;
    floatx4 s = *(const floatx4*)&Gpart[off];
#pragma unroll
    for (int z = 1; z < 8; ++z)
        s += *(const floatx4*)&Gpart[(size_t)z * stride + off];
    const int row = (int)(off / (size_t)KQ);
    const int c0  = (int)(off % (size_t)KQ);
    if (row >= c0 && row < c0 + 4) {
        float cs = 0.0f;
        for (int i = 0; i < NB; ++i) cs += part[(size_t)i * KQ + row];
        s[row - c0] = cs;
    }
    *(floatx4*)&G[off] = s;
}

// ---------------------------------------------------------------------------
extern "C" void kernel_launch(void* const* d_in, const int* in_sizes, int n_in,
                              void* d_out, int out_size, void* d_ws, size_t ws_size,
                              hipStream_t stream)
{
    (void)n_in; (void)out_size; (void)ws_size;
    const float* X      = (const float*)d_in[0];
    const float* z      = (const float*)d_in[1];
    const float* weight = (const float*)d_in[2];
    const float* mu     = (const float*)d_in[3];
    const float* stdv   = (const float*)d_in[4];
    const float* alpha  = (const float*)d_in[5];
    const float* vmw    = (const float*)d_in[6];
    const float* vsw    = (const float*)d_in[7];

    const int N  = in_sizes[0] / 8;   // 8192
    const int KQ = in_sizes[5];       // 1024
    const int NB = N / 64;            // 128 n-blocks

    unsigned short* ET = (unsigned short*)d_ws;                          // 16 MB
    float* Gpart = (float*)((char*)d_ws + (size_t)KQ * N * 2);           // 32 MB
    float* part  = (float*)((char*)d_ws + (size_t)KQ * N * 2
                            + 8ull * KQ * KQ * 4);                       // 512 KB

    float* Ephi = (float*)d_out;
    float* G    = Ephi + (size_t)N * KQ;
    float* Ecos = G + (size_t)KQ * KQ;

    k_ephi<<<dim3(KQ / 64, NB), 256, 0, stream>>>(
        X, z, weight, mu, stdv, alpha, vmw, vsw, Ephi, Ecos, ET, part, N);
    k_gemm<<<512, 256, 0, stream>>>(ET, Gpart, N, KQ);
    k_reduce<<<(KQ * KQ) / 1024, 256, 0, stream>>>(Gpart, part, G, KQ, NB);
}

// Round 6
// 140.594 us; speedup vs baseline: 1.1981x; 1.1981x over previous
//
#include <hip/hip_runtime.h>

#define TWO_PI 6.2831853071795864769f

typedef float floatx4 __attribute__((ext_vector_type(4)));
typedef float f32x16 __attribute__((ext_vector_type(16)));
typedef __bf16 bf16x8 __attribute__((ext_vector_type(8)));

__device__ __forceinline__ unsigned short f32_to_bf16(float f) {
    unsigned int u = __float_as_uint(f);
    u += 0x7fffu + ((u >> 16) & 1u);   // round-to-nearest-even
    return (unsigned short)(u >> 16);
}

__device__ __forceinline__ void gload_lds16(const void* g, void* l) {
    __builtin_amdgcn_global_load_lds(
        (__attribute__((address_space(1))) unsigned int*)g,
        (__attribute__((address_space(3))) unsigned int*)l, 16, 0, 0);
}

// ---------------------------------------------------------------------------
// Precompute per-(d,kq) coefficients (separate tiny kernel — L2-speed).
// coef row (32 floats): Ac[0..7]=2pi*E_w, u[0..7]=(2pi*std_p)^2*vsw, z[0..7],
//                       alpha, sqrt(2w/K), 2w/K
// ---------------------------------------------------------------------------
__global__ __launch_bounds__(256) void k_precompute(
    const float* __restrict__ z, const float* __restrict__ weight,
    const float* __restrict__ mu, const float* __restrict__ stdv,
    const float* __restrict__ alpha, const float* __restrict__ vmw,
    const float* __restrict__ vsw, float* __restrict__ coef)
{
    int kq = blockIdx.x * blockDim.x + threadIdx.x;
    if (kq >= 1024) return;
    int q = kq & 15;
    float w = weight[q];
    float t2k = w * (2.0f / 64.0f);
    float* c = coef + (size_t)kq * 32;
#pragma unroll
    for (int d = 0; d < 8; ++d) {
        float m = mu[d * 16 + q];
        float s = stdv[d * 16 + q];
        float mean_p = 1.0f / (m + 1e-8f);
        float std_p  = 1.0f / (TWO_PI * s + 1e-8f);
        float Ew  = mean_p + std_p * vmw[d * 1024 + kq];
        float sp2 = std_p * TWO_PI;
        c[d]      = TWO_PI * Ew;
        c[8 + d]  = sp2 * sp2 * vsw[d * 1024 + kq];
        c[16 + d] = z[d * 1024 + kq];
    }
    c[24] = alpha[kq];
    c[25] = sqrtf(t2k);
    c[26] = t2k;
}

// ---------------------------------------------------------------------------
// Elementwise kernel: 64 n-rows x 64 kq-cols per block, 256 threads.
// Column partials -> part[kq][NB] (transposed: diag reducer reads contiguous).
// Nontemporal stores for write-once f32 outputs (keep L2 for ET).
// ---------------------------------------------------------------------------
__global__ __launch_bounds__(256) void k_ephi(
    const float* __restrict__ X, const float* __restrict__ coef,
    float* __restrict__ Ephi, float* __restrict__ Ecos,
    unsigned short* __restrict__ ET, float* __restrict__ part,
    int N, int NB)
{
    __shared__ float Xs[64][8];
    __shared__ unsigned short Ebf[64][66];   // [kq_local][n_local]
    __shared__ float red[256];

    const int tid = threadIdx.x;
    const int kq0 = blockIdx.x * 64;
    const int n0  = blockIdx.y * 64;

    for (int i = tid; i < 512; i += 256)
        Xs[i >> 3][i & 7] = X[(size_t)(n0 + (i >> 3)) * 8 + (i & 7)];
    __syncthreads();

    const int kql = tid & 63;
    const int kq  = kq0 + kql;
    const int nb  = (tid >> 6) * 16;

    const float* c = coef + (size_t)kq * 32;
    float Ac[8], u[8], zv[8];
    *(floatx4*)&Ac[0] = *(const floatx4*)(c + 0);
    *(floatx4*)&Ac[4] = *(const floatx4*)(c + 4);
    *(floatx4*)&u[0]  = *(const floatx4*)(c + 8);
    *(floatx4*)&u[4]  = *(const floatx4*)(c + 12);
    *(floatx4*)&zv[0] = *(const floatx4*)(c + 16);
    *(floatx4*)&zv[4] = *(const floatx4*)(c + 20);
    const float alp = c[24], sqw = c[25], t2k = c[26];

    float csum = 0.0f;
#pragma unroll 4
    for (int nl = 0; nl < 16; ++nl) {
        const int n = nb + nl;
        floatx4 xa = *(const floatx4*)&Xs[n][0];
        floatx4 xb = *(const floatx4*)&Xs[n][4];
        float ph = 0.0f, s = 0.0f;
#pragma unroll
        for (int d = 0; d < 4; ++d) {
            float t = xa[d] - zv[d];
            ph = fmaf(Ac[d], t, ph);
            s  = fmaf(u[d], t * t, s);
        }
#pragma unroll
        for (int d = 0; d < 4; ++d) {
            float t = xb[d] - zv[4 + d];
            ph = fmaf(Ac[4 + d], t, ph);
            s  = fmaf(u[4 + d], t * t, s);
        }
        float cw  = __cosf(alp + ph);           // |arg| <~ few hundred: err ~1e-5
        float dec = __expf(-0.5f * s);
        float ep  = sqw * dec * cw;
        float d2  = dec * dec;
        float c2w = fmaf(2.0f * cw, cw, -1.0f); // cos(2(alpha+phase))
        float ec  = t2k * fmaf(0.5f * d2 * d2, c2w, 0.5f);
        csum += ec;
        size_t idx = (size_t)(n0 + n) * 1024 + kq;
        __builtin_nontemporal_store(ep, &Ephi[idx]);
        __builtin_nontemporal_store(ec, &Ecos[idx]);
        Ebf[kql][n] = f32_to_bf16(ep);
    }
    red[tid] = csum;
    __syncthreads();
    if (tid < 64) {
        float v = red[tid] + red[tid + 64] + red[tid + 128] + red[tid + 192];
        part[(size_t)(kq0 + tid) * NB + blockIdx.y] = v;   // plain store
    }

    // transposed bf16 tile: ET[kq0+row][n0 .. n0+63]; 8 lanes per 128B row
    const int rw = tid >> 3;
    const int cw8 = tid & 7;
#pragma unroll
    for (int cc = 0; cc < 2; ++cc) {
        const int row = rw + cc * 32;
        const unsigned short* s8 = &Ebf[row][cw8 * 8];
        uint4 v;
        v.x = (unsigned)s8[0] | ((unsigned)s8[1] << 16);
        v.y = (unsigned)s8[2] | ((unsigned)s8[3] << 16);
        v.z = (unsigned)s8[4] | ((unsigned)s8[5] << 16);
        v.w = (unsigned)s8[6] | ((unsigned)s8[7] << 16);
        *(uint4*)&ET[(size_t)(kq0 + row) * N + n0 + cw8 * 8] = v;
    }
}

// ---------------------------------------------------------------------------
// Gpart[z] = E^T E over n-chunk z. Flat 512-block grid, z = bid % 8 so all
// 64 tile-blocks of chunk z co-reside on XCD z and its 2MB ET slice stays
// L2-resident. 128x128 tile, 4 waves (2x2), BK=64, double-buffered LDS,
// XOR chunk swizzle. (No setprio: null/negative on 2-phase structure.)
// ---------------------------------------------------------------------------
__global__ __launch_bounds__(256) void k_gemm(
    const unsigned short* __restrict__ ET, float* __restrict__ Gpart,
    int N, int KQ)
{
    __shared__ unsigned short At[2][128 * 64];
    __shared__ unsigned short Bt[2][128 * 64];

    const int tid  = threadIdx.x;
    const int wave = tid >> 6, lane = tid & 63;
    const int wi = wave >> 1, wj = wave & 1;

    const int bid = blockIdx.x;
    const int zc  = bid & 7;            // split-K chunk == XCD (perf heuristic only)
    const int t8  = bid >> 3;           // 0..63 tile index
    const int i0  = (t8 >> 3) * 128;
    const int j0  = (t8 & 7) * 128;
    const int NS = N >> 3;              // 1024 per split
    const int nbase = zc * NS;
    const int nsteps = NS >> 6;         // 16

    const int srow = tid >> 3;
    const int sch  = (tid & 7) ^ (srow & 7);
    const size_t gA = (size_t)(i0 + srow) * N + nbase + sch * 8;
    const size_t gB = (size_t)(j0 + srow) * N + nbase + sch * 8;

    f32x16 acc[2][2] = {};

    auto STAGE = [&](int buf, int noff) {
        unsigned short* la = &At[buf][wave * 512];
        unsigned short* lb = &Bt[buf][wave * 512];
#pragma unroll
        for (int b = 0; b < 4; ++b) {
            gload_lds16(ET + gA + (size_t)(b * 32) * N + noff, la + b * 2048);
            gload_lds16(ET + gB + (size_t)(b * 32) * N + noff, lb + b * 2048);
        }
    };

    STAGE(0, 0);
    asm volatile("s_waitcnt vmcnt(0)" ::: "memory");
    __syncthreads();

    for (int t = 0; t < nsteps; ++t) {
        const int buf = t & 1;
        if (t + 1 < nsteps) STAGE(buf ^ 1, (t + 1) * 64);

        const unsigned short* Ab = &At[buf][0];
        const unsigned short* Bb = &Bt[buf][0];
        bf16x8 a[2][4], b[2][4];
#pragma unroll
        for (int m = 0; m < 2; ++m) {
            const int r = wi * 64 + m * 32 + (lane & 31);
#pragma unroll
            for (int ks = 0; ks < 4; ++ks) {
                const int ch = (ks * 2 + (lane >> 5)) ^ (r & 7);
                a[m][ks] = *(const bf16x8*)&Ab[r * 64 + ch * 8];
            }
        }
#pragma unroll
        for (int n = 0; n < 2; ++n) {
            const int r = wj * 64 + n * 32 + (lane & 31);
#pragma unroll
            for (int ks = 0; ks < 4; ++ks) {
                const int ch = (ks * 2 + (lane >> 5)) ^ (r & 7);
                b[n][ks] = *(const bf16x8*)&Bb[r * 64 + ch * 8];
            }
        }
#pragma unroll
        for (int ks = 0; ks < 4; ++ks)
#pragma unroll
            for (int m = 0; m < 2; ++m)
#pragma unroll
                for (int n = 0; n < 2; ++n)
                    acc[m][n] = __builtin_amdgcn_mfma_f32_32x32x16_bf16(
                        a[m][ks], b[n][ks], acc[m][n], 0, 0, 0);

        asm volatile("s_waitcnt vmcnt(0)" ::: "memory");
        __syncthreads();
    }

    // C/D layout (32x32): col = lane&31, row = (reg&3) + 8*(reg>>2) + 4*(lane>>5)
    float* Gp = Gpart + (size_t)zc * KQ * KQ;
    const int colb = j0 + wj * 64 + (lane & 31);
    const int rowb = i0 + wi * 64 + 4 * (lane >> 5);
#pragma unroll
    for (int m = 0; m < 2; ++m)
#pragma unroll
        for (int n = 0; n < 2; ++n)
#pragma unroll
            for (int reg = 0; reg < 16; ++reg) {
                const int row = rowb + m * 32 + (reg & 3) + 8 * (reg >> 2);
                Gp[(size_t)row * KQ + colb + n * 32] = acc[m][n][reg];
            }
}

// ---------------------------------------------------------------------------
// G = sum_z Gpart[z]; diag lane sums part[row][0..NB) via 32 float4 loads.
// ---------------------------------------------------------------------------
__global__ __launch_bounds__(256) void k_reduce(
    const float* __restrict__ Gpart, const float* __restrict__ part,
    float* __restrict__ G, int KQ, int NB)
{
    const size_t off = ((size_t)blockIdx.x * 256 + threadIdx.x) * 4;
    const size_t stride = (size_t)KQ * KQ;
    floatx4 s = *(const floatx4*)&Gpart[off];
#pragma unroll
    for (int z = 1; z < 8; ++z)
        s += *(const floatx4*)&Gpart[(size_t)z * stride + off];
    const int row = (int)(off / (size_t)KQ);
    const int c0  = (int)(off % (size_t)KQ);
    if (row >= c0 && row < c0 + 4) {
        const floatx4* p = (const floatx4*)&part[(size_t)row * NB];
        floatx4 a4 = p[0];
        for (int i = 1; i < (NB >> 2); ++i) a4 += p[i];
        s[row - c0] = a4[0] + a4[1] + a4[2] + a4[3];
    }
    *(floatx4*)&G[off] = s;
}

// ---------------------------------------------------------------------------
extern "C" void kernel_launch(void* const* d_in, const int* in_sizes, int n_in,
                              void* d_out, int out_size, void* d_ws, size_t ws_size,
                              hipStream_t stream)
{
    (void)n_in; (void)out_size; (void)ws_size;
    const float* X      = (const float*)d_in[0];
    const float* z      = (const float*)d_in[1];
    const float* weight = (const float*)d_in[2];
    const float* mu     = (const float*)d_in[3];
    const float* stdv   = (const float*)d_in[4];
    const float* alpha  = (const float*)d_in[5];
    const float* vmw    = (const float*)d_in[6];
    const float* vsw    = (const float*)d_in[7];

    const int N  = in_sizes[0] / 8;   // 8192
    const int KQ = in_sizes[5];       // 1024
    const int NB = N / 64;            // 128 n-blocks

    unsigned short* ET = (unsigned short*)d_ws;                          // 16 MB
    float* Gpart = (float*)((char*)d_ws + (size_t)KQ * N * 2);           // 32 MB
    float* part  = (float*)((char*)d_ws + (size_t)KQ * N * 2
                            + 8ull * KQ * KQ * 4);                       // 512 KB
    float* coef  = (float*)((char*)d_ws + (size_t)KQ * N * 2
                            + 8ull * KQ * KQ * 4 + (size_t)KQ * NB * 4); // 128 KB

    float* Ephi = (float*)d_out;
    float* G    = Ephi + (size_t)N * KQ;
    float* Ecos = G + (size_t)KQ * KQ;

    k_precompute<<<4, 256, 0, stream>>>(z, weight, mu, stdv, alpha, vmw, vsw, coef);
    k_ephi<<<dim3(KQ / 64, NB), 256, 0, stream>>>(
        X, coef, Ephi, Ecos, ET, part, N, NB);
    k_gemm<<<512, 256, 0, stream>>>(ET, Gpart, N, KQ);
    k_reduce<<<(KQ * KQ) / 1024, 256, 0, stream>>>(Gpart, part, G, KQ, NB);
}